// Round 9
// baseline (187.197 us; speedup 1.0000x reference)
//
#include <hip/hip_runtime.h>

// Problem constants (setup_inputs is fixed)
#define BATCH 2
#define NTXT  2048
#define TMED  4
#define MMED  256
#define TM    (TMED * MMED)      // 1024 kv rows per batch
#define DIM   1024
#define NH    16
#define DHD   64
#define KVW   2048               // k|v concatenated width
#define RMAX  256                // max real rows per batch via qpart fast path
#define QSTR  ((size_t)BATCH * RMAX * DIM)   // stride between qpart chunks

typedef _Float16 f16x8 __attribute__((ext_vector_type(8)));
typedef float    f32x4 __attribute__((ext_vector_type(4)));

// ---------------------------------------------------------------------------
// K1: blocks 0..1   : inclusive scan of locations -> txt_time + segment
//     block  2      : zero vbar|obar (contiguous 4096 floats)
//     blocks 3..514 : Wkv (K x N f32) -> WkvT (N x K f16) transpose
// ---------------------------------------------------------------------------
__global__ __launch_bounds__(256) void k1_prep(
    const int* __restrict__ loc, const float* __restrict__ Wkv,
    int* __restrict__ tt, int* __restrict__ seg, float* __restrict__ vbar,
    _Float16* __restrict__ WkvT) {
  __shared__ float tile[64][65];
  __shared__ int tots[256];
  __shared__ int s_start, s_end;
  const int bid = blockIdx.x;
  const int tid = threadIdx.x;
  if (bid < BATCH) {
    const int b = bid;
    if (tid == 0) { s_start = NTXT; s_end = NTXT; }
    __syncthreads();
    int v[8];
    int run = 0;
    const int base = b * NTXT + tid * 8;
#pragma unroll
    for (int k = 0; k < 8; k++) { run += loc[base + k]; v[k] = run; }
    tots[tid] = run; __syncthreads();
    for (int off = 1; off < 256; off <<= 1) {
      const int add = (tid >= off) ? tots[tid - off] : 0;
      __syncthreads();
      tots[tid] += add;
      __syncthreads();
    }
    const int excl = tots[tid] - run;
#pragma unroll
    for (int k = 0; k < 8; k++) {
      const int tv = excl + v[k];
      tt[base + k] = tv;
      if (tv >= 1) atomicMin(&s_start, tid * 8 + k);
      if (tv >= 5) atomicMin(&s_end, tid * 8 + k);
    }
    __syncthreads();
    if (tid == 0) {
      seg[b * 2]     = s_start;
      seg[b * 2 + 1] = s_end - s_start;
    }
  } else if (bid == 2) {
    for (int c = tid; c < 2 * BATCH * DIM; c += 256) vbar[c] = 0.f;
  } else {
    // ---- transpose+convert Wkv ----
    const int idx = bid - 3;                     // 0..511
    const int k0 = (idx & 15) * 64, n0 = (idx >> 4) * 64;
    const int r = tid >> 4, c4 = (tid & 15) * 4;
#pragma unroll
    for (int i = 0; i < 4; i++) {
      const float4 v = *reinterpret_cast<const float4*>(
          Wkv + (size_t)(k0 + r + i * 16) * KVW + n0 + c4);
      tile[r + i * 16][c4 + 0] = v.x; tile[r + i * 16][c4 + 1] = v.y;
      tile[r + i * 16][c4 + 2] = v.z; tile[r + i * 16][c4 + 3] = v.w;
    }
    __syncthreads();
#pragma unroll
    for (int it = 0; it < 2; it++) {
      const int chunk = it * 256 + tid;
      const int n = chunk >> 3, kc = (chunk & 7) * 8;
      f16x8 h;
#pragma unroll
      for (int j = 0; j < 8; j++) h[j] = (_Float16)tile[kc + j][n];
      *reinterpret_cast<f16x8*>(WkvT + (size_t)(n0 + n) * DIM + k0 + kc) = h;
    }
  }
}

// ---------------------------------------------------------------------------
// K2: blocks 0..63    : qproj with inline LayerNorm -> qpart[cc] (no atomics)
//     blocks 64..1087 : f16 MFMA GEMM kv16 = (f16)image @ WkvT^T
//                       64x64 tile, BK=32, 256 thr -> 4 blocks/CU
//                       + vbar epilogue (column sums of v-half, atomics)
// ---------------------------------------------------------------------------
__global__ __launch_bounds__(256) void k2_gemm_qproj(
    const float* __restrict__ image, const _Float16* __restrict__ WkvT,
    const float* __restrict__ text, const float* __restrict__ Wq,
    const float* __restrict__ gamma, const float* __restrict__ beta,
    const int* __restrict__ seg, _Float16* __restrict__ kv16,
    float* __restrict__ qpart, float* __restrict__ vbar) {
  __shared__ char smem[8192];
  const int idx = blockIdx.x;
  const int tid = threadIdx.x;
  if (idx >= 64) {
    // ---- GEMM 64x64 (A staged f32->f16 in-register) ----
    _Float16* As = (_Float16*)smem;          // 64*32 f16 = 4 KB
    _Float16* Bs = As + 64 * 32;             // 4 KB
    const int gid = idx - 64;                // 0..1023
    const int lane = tid & 63, wid = tid >> 6;
    const int wm = wid & 1, wn = wid >> 1;   // 2x2 waves
    const int row0 = (gid >> 5) * 64, col0 = (gid & 31) * 64;
    const int srow = tid >> 2, skc = (tid & 3) * 8;
    const int frow = lane & 15, fq = lane >> 4;
    f32x4 acc[2][2] = {};
    for (int k0 = 0; k0 < DIM; k0 += 32) {
      const float* ap = image + (size_t)(row0 + srow) * DIM + k0 + skc;
      const float4 a0 = *reinterpret_cast<const float4*>(ap);
      const float4 a1 = *reinterpret_cast<const float4*>(ap + 4);
      f16x8 av;
      av[0] = (_Float16)a0.x; av[1] = (_Float16)a0.y;
      av[2] = (_Float16)a0.z; av[3] = (_Float16)a0.w;
      av[4] = (_Float16)a1.x; av[5] = (_Float16)a1.y;
      av[6] = (_Float16)a1.z; av[7] = (_Float16)a1.w;
      const f16x8 bv = *reinterpret_cast<const f16x8*>(
          WkvT + (size_t)(col0 + srow) * DIM + k0 + skc);
      __syncthreads();
      *reinterpret_cast<f16x8*>(As + tid * 8) = av;
      *reinterpret_cast<f16x8*>(Bs + tid * 8) = bv;
      __syncthreads();
      f16x8 af[2], bf[2];
#pragma unroll
      for (int mt = 0; mt < 2; mt++)
        af[mt] = *reinterpret_cast<const f16x8*>(
            As + (wm * 32 + mt * 16 + frow) * 32 + fq * 8);
#pragma unroll
      for (int nt = 0; nt < 2; nt++)
        bf[nt] = *reinterpret_cast<const f16x8*>(
            Bs + (wn * 32 + nt * 16 + frow) * 32 + fq * 8);
#pragma unroll
      for (int mt = 0; mt < 2; mt++)
#pragma unroll
        for (int nt = 0; nt < 2; nt++)
          acc[mt][nt] = __builtin_amdgcn_mfma_f32_16x16x32_f16(
              af[mt], bf[nt], acc[mt][nt], 0, 0, 0);
    }
#pragma unroll
    for (int mt = 0; mt < 2; mt++)
#pragma unroll
      for (int nt = 0; nt < 2; nt++) {
        const int col = col0 + wn * 32 + nt * 16 + frow;
#pragma unroll
        for (int r = 0; r < 4; r++) {
          const int row = row0 + wm * 32 + mt * 16 + fq * 4 + r;
          kv16[(size_t)row * KVW + col] = (_Float16)acc[mt][nt][r];
        }
      }
    // ---- vbar epilogue: per-wave column sums over its 32-row band ----
    if (col0 >= DIM) {
      const int b = row0 >> 10;
#pragma unroll
      for (int nt = 0; nt < 2; nt++) {
        float s = 0.f;
#pragma unroll
        for (int mt = 0; mt < 2; mt++)
#pragma unroll
          for (int r = 0; r < 4; r++) s += acc[mt][nt][r];
        s += __shfl_down(s, 32);    // fq+2
        s += __shfl_down(s, 16);    // fq+1
        if (lane < 16)
          atomicAdd(&vbar[b * DIM + (col0 - DIM) + wn * 32 + nt * 16 + lane],
                    s * (1.0f / (float)TM));
      }
    }
  } else {
    // ---- qproj with inline LN: one wave per row for stats, 4 rows/iter ----
    float* tn_s = (float*)smem;              // 4 x 256 f32 = 4 KB
    const int j = idx;                       // 0..63
    const int b = j >> 5, nt = (j >> 2) & 7, cc = j & 3;
    const int n0 = nt * 128, c0 = cc * 256;
    const int lane = tid & 63, w = tid >> 6; // wave w handles row r0+w
    const int n = tid & 127, rh = tid >> 7;  // 2 row-halves
    const int i0 = seg[b * 2];
    const int cnt = min(seg[b * 2 + 1], RMAX);
    float* qp = qpart + (size_t)cc * QSTR;
    for (int r0 = 0; r0 < cnt; r0 += 4) {
      const int rows = min(4, cnt - r0);
      if (w < rows) {
        const float* xrow = text + (size_t)(b * NTXT + i0 + r0 + w) * DIM;
        float s = 0.f, sq = 0.f;
#pragma unroll
        for (int u = 0; u < 16; u++) {
          const float x = xrow[lane + 64 * u];
          s += x; sq += x * x;
        }
#pragma unroll
        for (int off = 32; off > 0; off >>= 1) {
          s += __shfl_xor(s, off);
          sq += __shfl_xor(sq, off);
        }
        const float mu = s * (1.0f / DIM);
        const float rstd = rsqrtf(sq * (1.0f / DIM) - mu * mu + 1e-5f);
#pragma unroll
        for (int u = 0; u < 4; u++) {
          const int c = c0 + lane + 64 * u;
          tn_s[w * 256 + lane + 64 * u] =
              (xrow[c] - mu) * rstd * gamma[c] + beta[c];
        }
      }
      __syncthreads();
      float a0 = 0.f, a1 = 0.f;
      for (int c = 0; c < 256; c++) {
        const float wv = Wq[(size_t)(c0 + c) * DIM + n0 + n];
        a0 += tn_s[(rh * 2) * 256 + c] * wv;
        a1 += tn_s[(rh * 2 + 1) * 256 + c] * wv;
      }
      if (rh * 2 < rows)
        qp[(size_t)(b * RMAX + r0 + rh * 2) * DIM + n0 + n] = a0;
      if (rh * 2 + 1 < rows)
        qp[(size_t)(b * RMAX + r0 + rh * 2 + 1) * DIM + n0 + n] = a1;
      __syncthreads();
    }
  }
}

// ---------------------------------------------------------------------------
// K3: obar[b,e] += vbar[b,c0:c0+128] @ Wo[c0:c0+128,e] (c-chunked, atomics)
// ---------------------------------------------------------------------------
__global__ __launch_bounds__(512) void k3_obar(
    const float* __restrict__ vbar, const float* __restrict__ Wo,
    float* __restrict__ obar) {
  __shared__ float vb_s[128];
  const int bid = blockIdx.x;                // 0..31
  const int tid = threadIdx.x;
  const int b = bid >> 4, et = (bid >> 3) & 1, cc = bid & 7;
  const int e = et * 512 + tid, c0 = cc * 128;
  if (tid < 128) vb_s[tid] = vbar[b * DIM + c0 + tid];
  __syncthreads();
  float s = 0.f;
  for (int c = 0; c < 128; c++)
    s += vb_s[c] * Wo[(size_t)(c0 + c) * DIM + e];
  atomicAdd(&obar[b * DIM + e], s);
}

// ---------------------------------------------------------------------------
// K4: blocks 0..4095    : fill (zero / obar / rare direct fallback)
//     blocks 4096..5119 : attnh (q from qpart, scores, softmax, PV -> oacc)
// ---------------------------------------------------------------------------
__global__ __launch_bounds__(256) void k4_fill_attn(
    const float* __restrict__ text, const _Float16* __restrict__ kv16,
    const float* __restrict__ Wq, const float* __restrict__ Wo,
    const float* __restrict__ gamma, const float* __restrict__ beta,
    const int* __restrict__ tt, const int* __restrict__ seg,
    const float* __restrict__ obar, const float* __restrict__ qpart,
    float* __restrict__ oacc, float* __restrict__ out) {
  __shared__ float red[256];
  __shared__ float pbuf[256];
  const int idx = blockIdx.x;
  const int tid = threadIdx.x;
  if (idx < BATCH * NTXT) {
    const int b = idx >> 11;
    const int i = idx & (NTXT - 1);
    const int t = tt[idx];
    float* orow = out + (size_t)idx * DIM;
    if (t == 0) {
      *reinterpret_cast<float4*>(&orow[tid * 4]) =
          make_float4(0.f, 0.f, 0.f, 0.f);
      return;
    }
    if (t > TMED) {
      *reinterpret_cast<float4*>(&orow[tid * 4]) =
          *reinterpret_cast<const float4*>(&obar[b * DIM + tid * 4]);
      return;
    }
    if (i - seg[b * 2] < RMAX) return;   // handled by attn blocks
    // ---- rare direct fallback (row beyond RMAX) ----
    __shared__ float tns[DIM];
    __shared__ float qrow[DIM];
    __shared__ float oaccs[DIM];
    const float* xrow = text + (size_t)idx * DIM;
    float x[4];
    float s = 0.f;
#pragma unroll
    for (int u = 0; u < 4; u++) { x[u] = xrow[tid + 256 * u]; s += x[u]; }
    red[tid] = s; __syncthreads();
    for (int st = 128; st > 0; st >>= 1) {
      if (tid < st) red[tid] += red[tid + st];
      __syncthreads();
    }
    const float mu = red[0] * (1.0f / DIM); __syncthreads();
    float vs = 0.f;
#pragma unroll
    for (int u = 0; u < 4; u++) { float d = x[u] - mu; vs += d * d; }
    red[tid] = vs; __syncthreads();
    for (int st = 128; st > 0; st >>= 1) {
      if (tid < st) red[tid] += red[tid + st];
      __syncthreads();
    }
    const float rstd = rsqrtf(red[0] * (1.0f / DIM) + 1e-5f); __syncthreads();
#pragma unroll
    for (int u = 0; u < 4; u++) {
      const int c = tid + 256 * u;
      tns[c] = (x[u] - mu) * rstd * gamma[c] + beta[c];
    }
    __syncthreads();
    {
      float qa[4] = {0.f, 0.f, 0.f, 0.f};
      for (int c = 0; c < DIM; c++) {
        const float tv = tns[c];
        const float* wp = Wq + (size_t)c * DIM + tid;
#pragma unroll
        for (int u = 0; u < 4; u++) qa[u] += tv * wp[256 * u];
      }
#pragma unroll
      for (int u = 0; u < 4; u++) qrow[tid + 256 * u] = qa[u];
    }
    __syncthreads();
    const size_t kvrow0 = (size_t)(b * TM + (t - 1) * MMED) * KVW;
    const int d0 = tid & 63, g = tid >> 6;
    for (int h = 0; h < NH; h++) {
      const _Float16* krow = kv16 + kvrow0 + (size_t)tid * KVW + h * DHD;
      float sc = 0.f;
#pragma unroll
      for (int d = 0; d < DHD; d++) sc += qrow[h * DHD + d] * (float)krow[d];
      sc *= 0.125f;
      red[tid] = sc; __syncthreads();
      for (int st = 128; st > 0; st >>= 1) {
        if (tid < st) red[tid] = fmaxf(red[tid], red[tid + st]);
        __syncthreads();
      }
      const float mx = red[0]; __syncthreads();
      const float e = __expf(sc - mx);
      red[tid] = e; __syncthreads();
      for (int st = 128; st > 0; st >>= 1) {
        if (tid < st) red[tid] += red[tid + st];
        __syncthreads();
      }
      const float inv = 1.0f / red[0]; __syncthreads();
      pbuf[tid] = e * inv; __syncthreads();
      const _Float16* vbase =
          kv16 + kvrow0 + (size_t)(g * 64) * KVW + DIM + h * DHD + d0;
      float a = 0.f;
#pragma unroll 8
      for (int jj = 0; jj < 64; jj++)
        a += pbuf[g * 64 + jj] * (float)vbase[(size_t)jj * KVW];
      red[tid] = a; __syncthreads();
      if (tid < 64)
        oaccs[h * DHD + tid] =
            red[tid] + red[64 + tid] + red[128 + tid] + red[192 + tid];
      __syncthreads();
    }
    float oa[4] = {0.f, 0.f, 0.f, 0.f};
    for (int c = 0; c < DIM; c++) {
      const float ov = oaccs[c];
      const float* wp = Wo + (size_t)c * DIM + tid;
#pragma unroll
      for (int u = 0; u < 4; u++) oa[u] += ov * wp[256 * u];
    }
#pragma unroll
    for (int u = 0; u < 4; u++) orow[tid + 256 * u] = oa[u];
  } else {
    // ---- attnh -> oacc ----
    __shared__ float qs[DHD];
    const int j = idx - BATCH * NTXT;       // 0..1023
    const int h = j & 15, rt = (j >> 4) & 31, b = j >> 9;
    const int i0 = seg[b * 2];
    const int cnt = min(seg[b * 2 + 1], RMAX);
    const int d0 = tid & 63, g = tid >> 6;
    for (int r = rt; r < cnt; r += 32) {
      const int i = i0 + r;
      const int t = tt[b * NTXT + i];       // in [1, TMED]
      if (tid < 64) {
        const size_t qoff = (size_t)(b * RMAX + r) * DIM + h * DHD + tid;
        qs[tid] = qpart[qoff] + qpart[QSTR + qoff] +
                  qpart[2 * QSTR + qoff] + qpart[3 * QSTR + qoff];
      }
      __syncthreads();
      const size_t kvrow0 = (size_t)(b * TM + (t - 1) * MMED) * KVW;
      const _Float16* krow = kv16 + kvrow0 + (size_t)tid * KVW + h * DHD;
      float sc = 0.f;
#pragma unroll
      for (int d = 0; d < DHD; d += 8) {
        const f16x8 kk = *reinterpret_cast<const f16x8*>(krow + d);
#pragma unroll
        for (int u = 0; u < 8; u++) sc += qs[d + u] * (float)kk[u];
      }
      sc *= 0.125f;
      red[tid] = sc; __syncthreads();
      for (int st = 128; st > 0; st >>= 1) {
        if (tid < st) red[tid] = fmaxf(red[tid], red[tid + st]);
        __syncthreads();
      }
      const float mx = red[0]; __syncthreads();
      const float e = __expf(sc - mx);
      red[tid] = e; __syncthreads();
      for (int st = 128; st > 0; st >>= 1) {
        if (tid < st) red[tid] += red[tid + st];
        __syncthreads();
      }
      const float inv = 1.0f / red[0]; __syncthreads();
      pbuf[tid] = e * inv; __syncthreads();
      const _Float16* vbase =
          kv16 + kvrow0 + (size_t)(g * 64) * KVW + DIM + h * DHD + d0;
      float a = 0.f;
#pragma unroll 8
      for (int jj = 0; jj < 64; jj++)
        a += pbuf[g * 64 + jj] * (float)vbase[(size_t)jj * KVW];
      red[tid] = a; __syncthreads();
      if (tid < 64)
        oacc[(size_t)(b * RMAX + r) * DIM + h * DHD + tid] =
            red[tid] + red[64 + tid] + red[128 + tid] + red[192 + tid];
      __syncthreads();
    }
  }
}

// ---------------------------------------------------------------------------
// K5: output projection for real rows. grid (16, 32, BATCH)
// ---------------------------------------------------------------------------
__global__ __launch_bounds__(256) void k5_oproj(
    const float* __restrict__ oacc, const float* __restrict__ Wo,
    const int* __restrict__ seg, float* __restrict__ out) {
  const int ct = blockIdx.x;
  const int rt = blockIdx.y;
  const int b = blockIdx.z;
  const int i0 = seg[b * 2];
  const int cnt = min(seg[b * 2 + 1], RMAX);
  const int tid = threadIdx.x;
  const int d0 = tid & 63, g = tid >> 6;
  __shared__ float op[4][64];
  for (int r = rt; r < cnt; r += 32) {
    const float* arow = oacc + (size_t)(b * RMAX + r) * DIM;
    const float* wo = Wo + (size_t)(g * 256) * DIM + ct * 64 + d0;
    float s = 0.f;
    for (int c = 0; c < 256; c++) s += arow[g * 256 + c] * wo[(size_t)c * DIM];
    op[g][d0] = s; __syncthreads();
    if (tid < 64)
      out[(size_t)(b * NTXT + i0 + r) * DIM + ct * 64 + tid] =
          op[0][tid] + op[1][tid] + op[2][tid] + op[3][tid];
    __syncthreads();
  }
}

// ---------------------------------------------------------------------------
extern "C" void kernel_launch(void* const* d_in, const int* in_sizes, int n_in,
                              void* d_out, int out_size, void* d_ws, size_t ws_size,
                              hipStream_t stream) {
  const float* text  = (const float*)d_in[0];
  const float* image = (const float*)d_in[1];
  const int*   loc   = (const int*)d_in[2];
  const float* Wq    = (const float*)d_in[3];
  const float* Wkv   = (const float*)d_in[4];
  const float* Wo    = (const float*)d_in[5];
  const float* gamma = (const float*)d_in[6];
  const float* beta  = (const float*)d_in[7];
  float* out = (float*)d_out;

  // ws layout: kv16 8MB | WkvT 4MB (aliased by oacc 2MB after k2) |
  //            qpart 4x2MB | vbar | obar | tt | seg
  _Float16* kv16  = (_Float16*)d_ws;
  _Float16* WkvT  = kv16 + (size_t)BATCH * TM * KVW;
  float*    oacc  = (float*)WkvT;                      // alias: k4/k5 > k2 use
  float*    qpart = (float*)(WkvT + (size_t)KVW * DIM);
  float*    vbar  = qpart + 4 * QSTR;
  float*    obar  = vbar + BATCH * DIM;
  int*      tt    = (int*)(obar + BATCH * DIM);
  int*      seg   = tt + BATCH * NTXT;

  k1_prep<<<515, 256, 0, stream>>>(loc, Wkv, tt, seg, vbar, WkvT);
  k2_gemm_qproj<<<1088, 256, 0, stream>>>(image, WkvT, text, Wq, gamma, beta,
                                          seg, kv16, qpart, vbar);
  k3_obar<<<32, 512, 0, stream>>>(vbar, Wo, obar);
  k4_fill_attn<<<BATCH * NTXT + NH * 32 * BATCH, 256, 0, stream>>>(
      text, kv16, Wq, Wo, gamma, beta, tt, seg, obar, qpart, oacc, out);
  k5_oproj<<<dim3(16, 32, BATCH), 256, 0, stream>>>(oacc, Wo, seg, out);
}

// Round 10
// 178.587 us; speedup vs baseline: 1.0482x; 1.0482x over previous
//
#include <hip/hip_runtime.h>

// Problem constants (setup_inputs is fixed)
#define BATCH 2
#define NTXT  2048
#define TMED  4
#define MMED  256
#define TM    (TMED * MMED)      // 1024 kv rows per batch
#define DIM   1024
#define NH    16
#define DHD   64
#define KVW   2048               // k|v concatenated width
#define RMAX  256                // max real rows per batch via qpart fast path
#define QSTR  ((size_t)BATCH * RMAX * DIM)   // stride between qpart chunks
#define BD    (BATCH * DIM)                  // stride between vpart/opart chunks

typedef _Float16 f16x8 __attribute__((ext_vector_type(8)));
typedef float    f32x4 __attribute__((ext_vector_type(4)));

// ---------------------------------------------------------------------------
// K1: blocks 0..1   : inclusive scan of locations -> txt_time + segment
//     blocks 2..65  : vpart[cc][b][e] = (mean_j image[b,:,c-chunk]) @ Wkv_v
//                     (exact fp32 partials, no atomics, no zero-init)
//     blocks 66..577: Wkv (K x N f32) -> WkvT (N x K f16) transpose
// ---------------------------------------------------------------------------
__global__ __launch_bounds__(256) void k1_prep(
    const int* __restrict__ loc, const float* __restrict__ Wkv,
    const float* __restrict__ image, int* __restrict__ tt,
    int* __restrict__ seg, _Float16* __restrict__ WkvT,
    float* __restrict__ vpart) {
  __shared__ float tile[64][65];
  __shared__ int tots[256];
  __shared__ int s_start, s_end;
  const int bid = blockIdx.x;
  const int tid = threadIdx.x;
  if (bid < BATCH) {
    const int b = bid;
    if (tid == 0) { s_start = NTXT; s_end = NTXT; }
    __syncthreads();
    int v[8];
    int run = 0;
    const int base = b * NTXT + tid * 8;
#pragma unroll
    for (int k = 0; k < 8; k++) { run += loc[base + k]; v[k] = run; }
    tots[tid] = run; __syncthreads();
    for (int off = 1; off < 256; off <<= 1) {
      const int add = (tid >= off) ? tots[tid - off] : 0;
      __syncthreads();
      tots[tid] += add;
      __syncthreads();
    }
    const int excl = tots[tid] - run;
#pragma unroll
    for (int k = 0; k < 8; k++) {
      const int tv = excl + v[k];
      tt[base + k] = tv;
      if (tv >= 1) atomicMin(&s_start, tid * 8 + k);
      if (tv >= 5) atomicMin(&s_end, tid * 8 + k);
    }
    __syncthreads();
    if (tid == 0) {
      seg[b * 2]     = s_start;
      seg[b * 2 + 1] = s_end - s_start;
    }
  } else if (bid < 66) {
    // ---- vpart: c-chunk of 32 ----
    float* part = (float*)tile;                  // 8 x 32
    const int j = bid - 2;                       // 0..63
    const int b = j >> 5, cc = j & 31;
    const int c0 = cc * 32;
    const int c = tid & 31, jg = tid >> 5;       // 8 j-groups of 128
    const float* p = image + (size_t)(b * TM + jg * 128) * DIM + c0 + c;
    float s = 0.f;
#pragma unroll 4
    for (int j2 = 0; j2 < 128; j2++) s += p[(size_t)j2 * DIM];
    part[jg * 32 + c] = s;
    __syncthreads();
    if (tid < 32) {
      float t2 = 0.f;
#pragma unroll
      for (int g = 0; g < 8; g++) t2 += part[g * 32 + tid];
      part[tid] = t2 * (1.0f / (float)TM);       // ibar chunk
    }
    __syncthreads();
    float a4[4] = {};
    for (int c2 = 0; c2 < 32; c2++) {
      const float ib = part[c2];
      const float* wrow = Wkv + (size_t)(c0 + c2) * KVW + DIM + tid;
#pragma unroll
      for (int u = 0; u < 4; u++) a4[u] += ib * wrow[u * 256];
    }
#pragma unroll
    for (int u = 0; u < 4; u++)
      vpart[(size_t)cc * BD + b * DIM + tid + u * 256] = a4[u];
  } else {
    // ---- transpose+convert Wkv ----
    const int idx = bid - 66;                    // 0..511
    const int k0 = (idx & 15) * 64, n0 = (idx >> 4) * 64;
    const int r = tid >> 4, c4 = (tid & 15) * 4;
#pragma unroll
    for (int i = 0; i < 4; i++) {
      const float4 v = *reinterpret_cast<const float4*>(
          Wkv + (size_t)(k0 + r + i * 16) * KVW + n0 + c4);
      tile[r + i * 16][c4 + 0] = v.x; tile[r + i * 16][c4 + 1] = v.y;
      tile[r + i * 16][c4 + 2] = v.z; tile[r + i * 16][c4 + 3] = v.w;
    }
    __syncthreads();
#pragma unroll
    for (int it = 0; it < 2; it++) {
      const int chunk = it * 256 + tid;
      const int n = chunk >> 3, kc = (chunk & 7) * 8;
      f16x8 h;
#pragma unroll
      for (int j = 0; j < 8; j++) h[j] = (_Float16)tile[kc + j][n];
      *reinterpret_cast<f16x8*>(WkvT + (size_t)(n0 + n) * DIM + k0 + kc) = h;
    }
  }
}

// ---------------------------------------------------------------------------
// K2: blocks 0..63  : qproj with inline LayerNorm -> qpart[cc] (no atomics)
//     blocks 64..79 : opart[cc][b][e2] = vbar[e-chunk] @ Wo[e-chunk, e2]
//     blocks 80..591: f16 MFMA GEMM kv16 = (f16)image @ WkvT^T
//                     128x64 tile, BK=32, 256 thr, 512 blocks (2/CU)
// ---------------------------------------------------------------------------
__global__ __launch_bounds__(256) void k2_gemm_qproj_opart(
    const float* __restrict__ image, const _Float16* __restrict__ WkvT,
    const float* __restrict__ text, const float* __restrict__ Wq,
    const float* __restrict__ Wo, const float* __restrict__ gamma,
    const float* __restrict__ beta, const int* __restrict__ seg,
    const float* __restrict__ vpart, _Float16* __restrict__ kv16,
    float* __restrict__ qpart, float* __restrict__ opart) {
  __shared__ char smem[12288];
  const int idx = blockIdx.x;
  const int tid = threadIdx.x;
  if (idx < 64) {
    // ---- qproj with inline LN: one wave per row for stats, 4 rows/iter ----
    float* tn_s = (float*)smem;              // 4 x 256 f32 = 4 KB
    const int j = idx;                       // 0..63
    const int b = j >> 5, nt = (j >> 2) & 7, cc = j & 3;
    const int n0 = nt * 128, c0 = cc * 256;
    const int lane = tid & 63, w = tid >> 6; // wave w handles row r0+w
    const int n = tid & 127, rh = tid >> 7;  // 2 row-halves
    const int i0 = seg[b * 2];
    const int cnt = min(seg[b * 2 + 1], RMAX);
    float* qp = qpart + (size_t)cc * QSTR;
    for (int r0 = 0; r0 < cnt; r0 += 4) {
      const int rows = min(4, cnt - r0);
      if (w < rows) {
        const float* xrow = text + (size_t)(b * NTXT + i0 + r0 + w) * DIM;
        float s = 0.f, sq = 0.f;
#pragma unroll
        for (int u = 0; u < 16; u++) {
          const float x = xrow[lane + 64 * u];
          s += x; sq += x * x;
        }
#pragma unroll
        for (int off = 32; off > 0; off >>= 1) {
          s += __shfl_xor(s, off);
          sq += __shfl_xor(sq, off);
        }
        const float mu = s * (1.0f / DIM);
        const float rstd = rsqrtf(sq * (1.0f / DIM) - mu * mu + 1e-5f);
#pragma unroll
        for (int u = 0; u < 4; u++) {
          const int c = c0 + lane + 64 * u;
          tn_s[w * 256 + lane + 64 * u] =
              (xrow[c] - mu) * rstd * gamma[c] + beta[c];
        }
      }
      __syncthreads();
      float a0 = 0.f, a1 = 0.f;
      for (int c = 0; c < 256; c++) {
        const float wv = Wq[(size_t)(c0 + c) * DIM + n0 + n];
        a0 += tn_s[(rh * 2) * 256 + c] * wv;
        a1 += tn_s[(rh * 2 + 1) * 256 + c] * wv;
      }
      if (rh * 2 < rows)
        qp[(size_t)(b * RMAX + r0 + rh * 2) * DIM + n0 + n] = a0;
      if (rh * 2 + 1 < rows)
        qp[(size_t)(b * RMAX + r0 + rh * 2 + 1) * DIM + n0 + n] = a1;
      __syncthreads();
    }
  } else if (idx < 80) {
    // ---- opart: e-chunk of 128 ----
    float* vb_s = (float*)smem;              // 128 f32
    const int j = idx - 64;                  // 0..15
    const int b = j >> 3, cc = j & 7;
    const int e0 = cc * 128;
    if (tid < 128) {
      float s = 0.f;
#pragma unroll 8
      for (int ch = 0; ch < 32; ch++)
        s += vpart[(size_t)ch * BD + b * DIM + e0 + tid];
      vb_s[tid] = s;
    }
    __syncthreads();
    float a4[4] = {};
    for (int c = 0; c < 128; c++) {
      const float vv = vb_s[c];
      const float* wrow = Wo + (size_t)(e0 + c) * DIM + tid;
#pragma unroll
      for (int u = 0; u < 4; u++) a4[u] += vv * wrow[u * 256];
    }
#pragma unroll
    for (int u = 0; u < 4; u++)
      opart[(size_t)cc * BD + b * DIM + tid + u * 256] = a4[u];
  } else {
    // ---- GEMM 128x64 (A staged f32->f16 in-register) ----
    _Float16* As = (_Float16*)smem;          // 128*32 f16 = 8 KB
    _Float16* Bs = As + 128 * 32;            // 64*32 f16 = 4 KB
    const int gid = idx - 80;                // 0..511
    const int lane = tid & 63, wid = tid >> 6;
    const int wm = wid & 1, wn = wid >> 1;   // 2 m-halves x 2 n-halves
    const int row0 = (gid >> 5) * 128, col0 = (gid & 31) * 64;
    const int ar = tid >> 2, ak = (tid & 3) * 8;
    const int frow = lane & 15, fq = lane >> 4;
    f32x4 acc[4][2] = {};
    for (int k0 = 0; k0 < DIM; k0 += 32) {
      f16x8 av[2];
#pragma unroll
      for (int s2 = 0; s2 < 2; s2++) {
        const float* ap =
            image + (size_t)(row0 + ar + s2 * 64) * DIM + k0 + ak;
        const float4 a0 = *reinterpret_cast<const float4*>(ap);
        const float4 a1 = *reinterpret_cast<const float4*>(ap + 4);
        av[s2][0] = (_Float16)a0.x; av[s2][1] = (_Float16)a0.y;
        av[s2][2] = (_Float16)a0.z; av[s2][3] = (_Float16)a0.w;
        av[s2][4] = (_Float16)a1.x; av[s2][5] = (_Float16)a1.y;
        av[s2][6] = (_Float16)a1.z; av[s2][7] = (_Float16)a1.w;
      }
      const f16x8 bv = *reinterpret_cast<const f16x8*>(
          WkvT + (size_t)(col0 + ar) * DIM + k0 + ak);
      __syncthreads();
      *reinterpret_cast<f16x8*>(As + ar * 32 + ak) = av[0];
      *reinterpret_cast<f16x8*>(As + (ar + 64) * 32 + ak) = av[1];
      *reinterpret_cast<f16x8*>(Bs + ar * 32 + ak) = bv;
      __syncthreads();
      f16x8 af[4], bf[2];
#pragma unroll
      for (int mt = 0; mt < 4; mt++)
        af[mt] = *reinterpret_cast<const f16x8*>(
            As + (wm * 64 + mt * 16 + frow) * 32 + fq * 8);
#pragma unroll
      for (int nt = 0; nt < 2; nt++)
        bf[nt] = *reinterpret_cast<const f16x8*>(
            Bs + (wn * 32 + nt * 16 + frow) * 32 + fq * 8);
#pragma unroll
      for (int mt = 0; mt < 4; mt++)
#pragma unroll
        for (int nt = 0; nt < 2; nt++)
          acc[mt][nt] = __builtin_amdgcn_mfma_f32_16x16x32_f16(
              af[mt], bf[nt], acc[mt][nt], 0, 0, 0);
    }
#pragma unroll
    for (int mt = 0; mt < 4; mt++)
#pragma unroll
      for (int nt = 0; nt < 2; nt++) {
        const int col = col0 + wn * 32 + nt * 16 + frow;
#pragma unroll
        for (int r = 0; r < 4; r++) {
          const int row = row0 + wm * 64 + mt * 16 + fq * 4 + r;
          kv16[(size_t)row * KVW + col] = (_Float16)acc[mt][nt][r];
        }
      }
  }
}

// ---------------------------------------------------------------------------
// K3: blocks 0..1023  : attnh (q from qpart, scores, softmax, PV -> oacc)
//     blocks 1024..1025: obar[b,e] = sum of 8 opart chunks
// ---------------------------------------------------------------------------
__global__ __launch_bounds__(256) void k3_attn_obar(
    const _Float16* __restrict__ kv16, const int* __restrict__ tt,
    const int* __restrict__ seg, const float* __restrict__ qpart,
    const float* __restrict__ opart, float* __restrict__ oacc,
    float* __restrict__ obar) {
  __shared__ float red[256];
  __shared__ float pbuf[256];
  __shared__ float qs[DHD];
  const int idx = blockIdx.x;
  const int tid = threadIdx.x;
  if (idx >= 1024) {
    const int b = idx - 1024;
    for (int e = tid; e < DIM; e += 256) {
      float s = 0.f;
#pragma unroll
      for (int cc = 0; cc < 8; cc++) s += opart[(size_t)cc * BD + b * DIM + e];
      obar[b * DIM + e] = s;
    }
    return;
  }
  const int h = idx & 15, rt = (idx >> 4) & 31, b = idx >> 9;
  const int i0 = seg[b * 2];
  const int cnt = min(seg[b * 2 + 1], RMAX);
  const int d0 = tid & 63, g = tid >> 6;
  for (int r = rt; r < cnt; r += 32) {
    const int i = i0 + r;
    const int t = tt[b * NTXT + i];       // in [1, TMED]
    if (tid < 64) {
      const size_t qoff = (size_t)(b * RMAX + r) * DIM + h * DHD + tid;
      qs[tid] = qpart[qoff] + qpart[QSTR + qoff] +
                qpart[2 * QSTR + qoff] + qpart[3 * QSTR + qoff];
    }
    __syncthreads();
    const size_t kvrow0 = (size_t)(b * TM + (t - 1) * MMED) * KVW;
    const _Float16* krow = kv16 + kvrow0 + (size_t)tid * KVW + h * DHD;
    float sc = 0.f;
#pragma unroll
    for (int d = 0; d < DHD; d += 8) {
      const f16x8 kk = *reinterpret_cast<const f16x8*>(krow + d);
#pragma unroll
      for (int u = 0; u < 8; u++) sc += qs[d + u] * (float)kk[u];
    }
    sc *= 0.125f;
    red[tid] = sc; __syncthreads();
    for (int st = 128; st > 0; st >>= 1) {
      if (tid < st) red[tid] = fmaxf(red[tid], red[tid + st]);
      __syncthreads();
    }
    const float mx = red[0]; __syncthreads();
    const float e = __expf(sc - mx);
    red[tid] = e; __syncthreads();
    for (int st = 128; st > 0; st >>= 1) {
      if (tid < st) red[tid] += red[tid + st];
      __syncthreads();
    }
    const float inv = 1.0f / red[0]; __syncthreads();
    pbuf[tid] = e * inv; __syncthreads();
    const _Float16* vbase =
        kv16 + kvrow0 + (size_t)(g * 64) * KVW + DIM + h * DHD + d0;
    float a = 0.f;
#pragma unroll 8
    for (int jj = 0; jj < 64; jj++)
      a += pbuf[g * 64 + jj] * (float)vbase[(size_t)jj * KVW];
    red[tid] = a; __syncthreads();
    if (tid < 64)
      oacc[(size_t)(b * RMAX + r) * DIM + h * DHD + tid] =
          red[tid] + red[64 + tid] + red[128 + tid] + red[192 + tid];
    __syncthreads();
  }
}

// ---------------------------------------------------------------------------
// K4: blocks 0..4095    : fill (zero / obar / rare direct fallback)
//     blocks 4096..5119 : oproj for real rows
// ---------------------------------------------------------------------------
__global__ __launch_bounds__(256) void k4_fill_oproj(
    const float* __restrict__ text, const _Float16* __restrict__ kv16,
    const float* __restrict__ Wq, const float* __restrict__ Wo,
    const float* __restrict__ gamma, const float* __restrict__ beta,
    const int* __restrict__ tt, const int* __restrict__ seg,
    const float* __restrict__ obar, const float* __restrict__ oacc,
    float* __restrict__ out) {
  __shared__ float red[256];
  __shared__ float pbuf[256];
  const int idx = blockIdx.x;
  const int tid = threadIdx.x;
  if (idx < BATCH * NTXT) {
    const int b = idx >> 11;
    const int i = idx & (NTXT - 1);
    const int t = tt[idx];
    float* orow = out + (size_t)idx * DIM;
    if (t == 0) {
      *reinterpret_cast<float4*>(&orow[tid * 4]) =
          make_float4(0.f, 0.f, 0.f, 0.f);
      return;
    }
    if (t > TMED) {
      *reinterpret_cast<float4*>(&orow[tid * 4]) =
          *reinterpret_cast<const float4*>(&obar[b * DIM + tid * 4]);
      return;
    }
    if (i - seg[b * 2] < RMAX) return;   // handled by attn + oproj
    // ---- rare direct fallback (row beyond RMAX) ----
    __shared__ float tns[DIM];
    __shared__ float qrow[DIM];
    __shared__ float oaccs[DIM];
    const float* xrow = text + (size_t)idx * DIM;
    float x[4];
    float s = 0.f;
#pragma unroll
    for (int u = 0; u < 4; u++) { x[u] = xrow[tid + 256 * u]; s += x[u]; }
    red[tid] = s; __syncthreads();
    for (int st = 128; st > 0; st >>= 1) {
      if (tid < st) red[tid] += red[tid + st];
      __syncthreads();
    }
    const float mu = red[0] * (1.0f / DIM); __syncthreads();
    float vs = 0.f;
#pragma unroll
    for (int u = 0; u < 4; u++) { float d = x[u] - mu; vs += d * d; }
    red[tid] = vs; __syncthreads();
    for (int st = 128; st > 0; st >>= 1) {
      if (tid < st) red[tid] += red[tid + st];
      __syncthreads();
    }
    const float rstd = rsqrtf(red[0] * (1.0f / DIM) + 1e-5f); __syncthreads();
#pragma unroll
    for (int u = 0; u < 4; u++) {
      const int c = tid + 256 * u;
      tns[c] = (x[u] - mu) * rstd * gamma[c] + beta[c];
    }
    __syncthreads();
    {
      float qa[4] = {0.f, 0.f, 0.f, 0.f};
      for (int c = 0; c < DIM; c++) {
        const float tv = tns[c];
        const float* wp = Wq + (size_t)c * DIM + tid;
#pragma unroll
        for (int u = 0; u < 4; u++) qa[u] += tv * wp[256 * u];
      }
#pragma unroll
      for (int u = 0; u < 4; u++) qrow[tid + 256 * u] = qa[u];
    }
    __syncthreads();
    const size_t kvrow0 = (size_t)(b * TM + (t - 1) * MMED) * KVW;
    const int d0 = tid & 63, g = tid >> 6;
    for (int h = 0; h < NH; h++) {
      const _Float16* krow = kv16 + kvrow0 + (size_t)tid * KVW + h * DHD;
      float sc = 0.f;
#pragma unroll
      for (int d = 0; d < DHD; d++) sc += qrow[h * DHD + d] * (float)krow[d];
      sc *= 0.125f;
      red[tid] = sc; __syncthreads();
      for (int st = 128; st > 0; st >>= 1) {
        if (tid < st) red[tid] = fmaxf(red[tid], red[tid + st]);
        __syncthreads();
      }
      const float mx = red[0]; __syncthreads();
      const float e = __expf(sc - mx);
      red[tid] = e; __syncthreads();
      for (int st = 128; st > 0; st >>= 1) {
        if (tid < st) red[tid] += red[tid + st];
        __syncthreads();
      }
      const float inv = 1.0f / red[0]; __syncthreads();
      pbuf[tid] = e * inv; __syncthreads();
      const _Float16* vbase =
          kv16 + kvrow0 + (size_t)(g * 64) * KVW + DIM + h * DHD + d0;
      float a = 0.f;
#pragma unroll 8
      for (int jj = 0; jj < 64; jj++)
        a += pbuf[g * 64 + jj] * (float)vbase[(size_t)jj * KVW];
      red[tid] = a; __syncthreads();
      if (tid < 64)
        oaccs[h * DHD + tid] =
            red[tid] + red[64 + tid] + red[128 + tid] + red[192 + tid];
      __syncthreads();
    }
    float oa[4] = {0.f, 0.f, 0.f, 0.f};
    for (int c = 0; c < DIM; c++) {
      const float ov = oaccs[c];
      const float* wp = Wo + (size_t)c * DIM + tid;
#pragma unroll
      for (int u = 0; u < 4; u++) oa[u] += ov * wp[256 * u];
    }
#pragma unroll
    for (int u = 0; u < 4; u++) orow[tid + 256 * u] = oa[u];
  } else {
    // ---- oproj for real rows ----
    __shared__ float op[4][64];
    const int j = idx - BATCH * NTXT;       // 0..1023
    const int ct = j & 15, rt = (j >> 4) & 31, b = j >> 9;
    const int i0 = seg[b * 2];
    const int cnt = min(seg[b * 2 + 1], RMAX);
    const int d0 = tid & 63, g = tid >> 6;
    for (int r = rt; r < cnt; r += 32) {
      const float* arow = oacc + (size_t)(b * RMAX + r) * DIM;
      const float* wo = Wo + (size_t)(g * 256) * DIM + ct * 64 + d0;
      float s = 0.f;
      for (int c = 0; c < 256; c++)
        s += arow[g * 256 + c] * wo[(size_t)c * DIM];
      op[g][d0] = s; __syncthreads();
      if (tid < 64)
        out[(size_t)(b * NTXT + i0 + r) * DIM + ct * 64 + tid] =
            op[0][tid] + op[1][tid] + op[2][tid] + op[3][tid];
      __syncthreads();
    }
  }
}

// ---------------------------------------------------------------------------
extern "C" void kernel_launch(void* const* d_in, const int* in_sizes, int n_in,
                              void* d_out, int out_size, void* d_ws, size_t ws_size,
                              hipStream_t stream) {
  const float* text  = (const float*)d_in[0];
  const float* image = (const float*)d_in[1];
  const int*   loc   = (const int*)d_in[2];
  const float* Wq    = (const float*)d_in[3];
  const float* Wkv   = (const float*)d_in[4];
  const float* Wo    = (const float*)d_in[5];
  const float* gamma = (const float*)d_in[6];
  const float* beta  = (const float*)d_in[7];
  float* out = (float*)d_out;

  // ws layout: kv16 8MB | WkvT 4MB (aliased by oacc 2MB after K2) |
  //            qpart 4x2MB | vpart 256KB | opart 64KB | obar | tt | seg
  _Float16* kv16  = (_Float16*)d_ws;
  _Float16* WkvT  = kv16 + (size_t)BATCH * TM * KVW;
  float*    oacc  = (float*)WkvT;                     // alias: K3/K4 > K2 use
  float*    qpart = (float*)(WkvT + (size_t)KVW * DIM);
  float*    vpart = qpart + 4 * QSTR;                 // 32 chunks x BD
  float*    opart = vpart + 32 * BD;                  // 8 chunks x BD
  float*    obar  = opart + 8 * BD;
  int*      tt    = (int*)(obar + BD);
  int*      seg   = tt + BATCH * NTXT;

  k1_prep<<<578, 256, 0, stream>>>(loc, Wkv, image, tt, seg, WkvT, vpart);
  k2_gemm_qproj_opart<<<592, 256, 0, stream>>>(image, WkvT, text, Wq, Wo,
                                               gamma, beta, seg, vpart, kv16,
                                               qpart, opart);
  k3_attn_obar<<<1026, 256, 0, stream>>>(kv16, tt, seg, qpart, opart, oacc,
                                         obar);
  k4_fill_oproj<<<BATCH * NTXT + 1024, 256, 0, stream>>>(
      text, kv16, Wq, Wo, gamma, beta, tt, seg, obar, oacc, out);
}